// Round 3
// baseline (705.460 us; speedup 1.0000x reference)
//
#include <hip/hip_runtime.h>
#include <stdint.h>

// B=8, N=E=2048.  All-fp16 single-product pipeline:
//  1) Xh = fp16(X), Wh = fp16(W)
//  2) Q = Xh·Wh^T + b   -> fp16 Qh
//  3) S = Qh·Xh^T + gamma -> fp32  (+ fused column-softmax partial stats)
//  4) stats combine (8 partials -> Mx, Rs)
//  5) attn[b,m,e] = exp(S-M)*R -> fp16 (overlays Qh)
//  6) out = Xh·attn^T -> fp32
//
// R3 changes vs R2 (904 TF/GEMM, MfmaUtil 41%):
//  (a) MFMA shape 16x16x32 -> 32x32x16 f16: shape ceiling 1955->2178+ TF,
//      halves MFMA inst count (32/wave/tile), same LDS traffic.  acc[4][2]
//      f32x16.  A-frag: row=lane&31, k=(lane>>5)*8+j; C/D: col=lane&31,
//      row=(reg&3)+8*(reg>>2)+4*(lane>>5)  [m74/m101].
//  (b) stats_partial fused into GEMM2 epilogue (MODE 2): block owns a unique
//      256-row x 256-col slab of S -> per-column max & sum(exp) over its 256
//      rows -> Mp/Sp[(b*8+seg)*2048+col], no atomics.  Deletes a 128 MB
//      re-read dispatch.
//
// Sync skeleton identical to R2 (passed): 4 phases/tile, 2 SYNC/tile,
// vmcnt(8) steady ledger, 8 loads always in flight (see R2 ledger comment).
//
// LDS swizzle unchanged: 64-B rows, stored 16-B seg s_lds = s_g ^ ((r>>1)&3)
// (applied on the global fetch address), read with the inverse.  For the
// 32-row x 2-seg read pattern of 32x32 frags each bank still serves exactly
// 8 words/instruction -> conflict-free.

typedef _Float16 f16;
typedef f16 f16x8 __attribute__((ext_vector_type(8)));
typedef f16 f16x4 __attribute__((ext_vector_type(4)));
typedef float f32x4 __attribute__((ext_vector_type(4)));
typedef float f32x16 __attribute__((ext_vector_type(16)));

#define ND 2048
#define NNL 4194304L  // ND*ND
#define NT 32         // K tiles of 64

static __device__ __forceinline__ void stage16(const void* g, void* l) {
  __builtin_amdgcn_global_load_lds(
      (const __attribute__((address_space(1))) uint32_t*)g,
      (__attribute__((address_space(3))) uint32_t*)l, 16, 0, 0);
}

// ---------------- fp32 -> fp16 convert ----------------
__global__ void cvt_f16(const float* __restrict__ x, f16* __restrict__ h, int n4) {
  int i = blockIdx.x * 256 + threadIdx.x;
  if (i >= n4) return;
  float4 v = reinterpret_cast<const float4*>(x)[i];
  f16x4 o;
  o.x = (f16)v.x; o.y = (f16)v.y; o.z = (f16)v.z; o.w = (f16)v.w;
  reinterpret_cast<f16x4*>(h)[i] = o;
}

// region byte base within smem: d=dbuf(0/1), o=op(0=A,1=B), kh=K-half(0/1)
#define RB(d_, o_, kh_) ((((d_) << 2) | ((o_) << 1) | (kh_)) * 16384)

// stage one 16 KiB half-region (256 rows x 32 f16): 2 x 8 KiB load-rounds.
#define STG(gp_, ro_, t_, kh_)                                           \
  do {                                                                   \
    stage16((gp_) + (long)(t_) * 128 + (kh_) * 64, smem + (ro_) + ld0);  \
    stage16((gp_) + 524288L + (long)(t_) * 128 + (kh_) * 64,             \
            smem + (ro_) + ld1);                                         \
  } while (0)

#define FENCE asm volatile("" ::: "memory")

#define SYNC(vm_)                                                        \
  do {                                                                   \
    asm volatile("s_waitcnt vmcnt(" #vm_ ") lgkmcnt(0)" ::: "memory");   \
    __builtin_amdgcn_s_barrier();                                        \
    FENCE;                                                               \
  } while (0)

#define MFMA32(a_, b_, c_) \
  __builtin_amdgcn_mfma_f32_32x32x16_f16(a_, b_, c_, 0, 0, 0)

// One phase: p_ = mt-pair (mt = 2p, 2p+1), kh_ = K-half.  8 MFMAs.
// RDB_=1 also (re)loads the 4 B frags (reused by the following p_=1 phase).
#define PHASE32(d_, p_, kh_, RDB_, STAGE_)                                    \
  do {                                                                        \
    const char* ab_ = smem + RB(d_, 0, kh_) + (p_) * 4096;                    \
    f16x8 af0 = *(const f16x8*)(ab_ + aoff0);                                 \
    f16x8 af1 = *(const f16x8*)(ab_ + aoff1);                                 \
    f16x8 af2 = *(const f16x8*)(ab_ + aoff0 + 2048);                          \
    f16x8 af3 = *(const f16x8*)(ab_ + aoff1 + 2048);                          \
    if (RDB_) {                                                               \
      const char* bb_ = smem + RB(d_, 1, kh_);                                \
      bf[0] = *(const f16x8*)(bb_ + boff0);                                   \
      bf[1] = *(const f16x8*)(bb_ + boff1);                                   \
      bf[2] = *(const f16x8*)(bb_ + boff0 + 2048);                            \
      bf[3] = *(const f16x8*)(bb_ + boff1 + 2048);                            \
    }                                                                         \
    STAGE_                                                                    \
    __builtin_amdgcn_s_setprio(1);                                            \
    acc[(p_)*2][0]   = MFMA32(af0, bf[0], acc[(p_)*2][0]);                    \
    acc[(p_)*2][0]   = MFMA32(af1, bf[1], acc[(p_)*2][0]);                    \
    acc[(p_)*2][1]   = MFMA32(af0, bf[2], acc[(p_)*2][1]);                    \
    acc[(p_)*2][1]   = MFMA32(af1, bf[3], acc[(p_)*2][1]);                    \
    acc[(p_)*2+1][0] = MFMA32(af2, bf[0], acc[(p_)*2+1][0]);                  \
    acc[(p_)*2+1][0] = MFMA32(af3, bf[1], acc[(p_)*2+1][0]);                  \
    acc[(p_)*2+1][1] = MFMA32(af2, bf[2], acc[(p_)*2+1][1]);                  \
    acc[(p_)*2+1][1] = MFMA32(af3, bf[3], acc[(p_)*2+1][1]);                  \
    __builtin_amdgcn_s_setprio(0);                                            \
  } while (0)

// ---------------- GEMM: C[i,j] = dot(A[i,:], B[j,:])  (row-major, K=2048)
// MODE 1: + bias[j], fp16 store
// MODE 0: + optional gamma, fp32 store
// MODE 2: + gamma, fp32 store, fused column-softmax partials -> Mp/Sp
template <int MODE>
__launch_bounds__(512, 2) __global__
void gemm256(const f16* __restrict__ A, long sA, const f16* __restrict__ B, long sB,
             const float* __restrict__ bias, const float* __restrict__ gamma,
             float* __restrict__ Cf, f16* __restrict__ Ch,
             float* __restrict__ Mp, float* __restrict__ Sp) {
  __shared__ char smem[131072];

  const int bz = blockIdx.z;
  const long tm = (long)blockIdx.y * 256;
  const long tn = (long)blockIdx.x * 256;
  const int tid = threadIdx.x;
  const int lane = tid & 63;
  const int wid = tid >> 6;
  const int wm = (wid >> 2) << 7;  // 0 / 128
  const int wn = (wid & 3) << 6;   // 0 / 64 / 128 / 192

  // staging: linear idx16 = l*512 + tid -> row = idx>>2, s_lds = idx&3,
  // fetch global seg s_g = s_lds ^ ((row>>1)&3) = (tid&3)^((tid>>3)&3)
  const int sg = (tid & 3) ^ ((tid >> 3) & 3);
  const char* gA = (const char*)(A + bz * sA + tm * ND) + (long)(tid >> 2) * 4096 + sg * 16;
  const char* gB = (const char*)(B + bz * sB + tn * ND) + (long)(tid >> 2) * 4096 + sg * 16;
  const uint32_t ld0 = tid * 16u;
  const uint32_t ld1 = 8192u + tid * 16u;

  // 32x32x16 frag reader: row = base32 + (lane&31), logical seg q = kk*2+hi
  // (hi = lane>>5), LDS seg = q ^ ((row>>1)&3); row low bits = lane&31 only.
  const int r31 = lane & 31;
  const int hi = lane >> 5;
  const int axor = (r31 >> 1) & 3;
  const int segk0 = ((hi ^ axor) << 4);  // bytes; kk=1 seg = segk0 ^ 0x20
  const int aoff0 = (wm + r31) * 64 + segk0;
  const int aoff1 = aoff0 ^ 0x20;
  const int boff0 = (wn + r31) * 64 + segk0;
  const int boff1 = boff0 ^ 0x20;

  f32x16 acc[4][2] = {};
  f16x8 bf[4];

  // prologue: t0.k0, t0.k1, t1.k0 (12 loads); vmcnt(8) drains t0.k0 only,
  // leaving {t0.k1, t1.k0} = 8 in flight = steady state.
  STG(gA, RB(0, 0, 0), 0, 0);
  STG(gB, RB(0, 1, 0), 0, 0);
  STG(gA, RB(0, 0, 1), 0, 1);
  STG(gB, RB(0, 1, 1), 0, 1);
  STG(gA, RB(1, 0, 0), 1, 0);
  STG(gB, RB(1, 1, 0), 1, 0);
  asm volatile("s_waitcnt vmcnt(8)" ::: "memory");
  __builtin_amdgcn_s_barrier();
  FENCE;

#pragma unroll 2
  for (int t = 0; t < NT - 2; ++t) {
    const int d = t & 1;
    const int e = d ^ 1;
    PHASE32(d, 0, 0, 1, STG(gA, RB(e, 0, 1), t + 1, 1););
    PHASE32(d, 1, 0, 0, STG(gB, RB(e, 1, 1), t + 1, 1););
    SYNC(8);
    PHASE32(d, 0, 1, 1, STG(gA, RB(d, 0, 0), t + 2, 0););
    PHASE32(d, 1, 1, 0, STG(gB, RB(d, 1, 0), t + 2, 0););
    SYNC(8);
  }
  {  // t = NT-2 (even => d=0, e=1)
    PHASE32(0, 0, 0, 1, STG(gA, RB(1, 0, 1), NT - 1, 1););
    PHASE32(0, 1, 0, 0, STG(gB, RB(1, 1, 1), NT - 1, 1););
    SYNC(8);
    PHASE32(0, 0, 1, 1, ;);
    PHASE32(0, 1, 1, 0, ;);
    SYNC(4);  // drains (NT-1).k0; leaves (NT-1).k1 in flight
  }
  {  // t = NT-1 (odd => d=1)
    PHASE32(1, 0, 0, 1, ;);
    PHASE32(1, 1, 0, 0, ;);
    SYNC(0);  // drains (NT-1).k1 before its kh=1 reads
    PHASE32(1, 0, 1, 1, ;);
    PHASE32(1, 1, 1, 0, ;);
    // no sync: epilogue syncs itself where needed
  }

  // epilogue: C/D 32x32 layout col=lane&31, row=(reg&3)+8*(reg>>2)+4*hi
  const long cb = (long)bz * NNL;
  if constexpr (MODE == 1) {
#pragma unroll
    for (int nt = 0; nt < 2; ++nt) {
      const long col = tn + wn + nt * 32 + r31;
      const float bj = bias[col];
#pragma unroll
      for (int mt = 0; mt < 4; ++mt) {
#pragma unroll
        for (int r = 0; r < 16; ++r) {
          const long row = tm + wm + mt * 32 + (r & 3) + 8 * (r >> 2) + 4 * hi;
          Ch[cb + row * ND + col] = (f16)(acc[mt][nt][r] + bj);
        }
      }
    }
  } else if constexpr (MODE == 0) {
    const float g = gamma ? gamma[0] : 0.0f;
#pragma unroll
    for (int nt = 0; nt < 2; ++nt) {
      const long col = tn + wn + nt * 32 + r31;
#pragma unroll
      for (int mt = 0; mt < 4; ++mt) {
#pragma unroll
        for (int r = 0; r < 16; ++r) {
          const long row = tm + wm + mt * 32 + (r & 3) + 8 * (r >> 2) + 4 * hi;
          Cf[cb + row * ND + col] = acc[mt][nt][r] + g;
        }
      }
    }
  } else {  // MODE 2: fp32 store + gamma + fused column-softmax partials
    const float g = gamma[0];
    // ---- per-column (over this block's 256 rows) max & sum(exp) ----
    __syncthreads();  // all waves done reading smem -> safe to reuse
    float* redm = (float*)smem;        // [8 wid][2 nt][32 col] = 512
    float* reds = redm + 512;
#pragma unroll
    for (int nt = 0; nt < 2; ++nt) {
      float ml = -3.4e38f;
#pragma unroll
      for (int mt = 0; mt < 4; ++mt)
#pragma unroll
        for (int r = 0; r < 16; ++r)
          ml = fmaxf(ml, acc[mt][nt][r] + g);
      float sl = 0.f;
#pragma unroll
      for (int mt = 0; mt < 4; ++mt)
#pragma unroll
        for (int r = 0; r < 16; ++r)
          sl += __expf(acc[mt][nt][r] + g - ml);
      // combine lane <-> lane^32 (same column, other 4-row stripe)
      float pm = __shfl(ml, lane ^ 32, 64);
      float ps = __shfl(sl, lane ^ 32, 64);
      float m2 = fmaxf(ml, pm);
      float s2 = sl * __expf(ml - m2) + ps * __expf(pm - m2);
      if (hi == 0) {
        redm[(wid * 2 + nt) * 32 + r31] = m2;
        reds[(wid * 2 + nt) * 32 + r31] = s2;
      }
    }
    __syncthreads();
    if (tid < 256) {  // combine wm=0 / wm=128 wave pairs; col = tn + tid
      const int g4 = tid >> 6, nt2 = (tid >> 5) & 1, l5 = tid & 31;
      const float mA = redm[(g4 * 2 + nt2) * 32 + l5];
      const float sA = reds[(g4 * 2 + nt2) * 32 + l5];
      const float mB = redm[((4 + g4) * 2 + nt2) * 32 + l5];
      const float sB = reds[((4 + g4) * 2 + nt2) * 32 + l5];
      const float m = fmaxf(mA, mB);
      const float s = sA * __expf(mA - m) + sB * __expf(mB - m);
      const long o = ((long)bz * 8 + blockIdx.y) * ND + tn + tid;
      Mp[o] = m;
      Sp[o] = s;
    }
    // ---- S store ----
#pragma unroll
    for (int nt = 0; nt < 2; ++nt) {
      const long col = tn + wn + nt * 32 + r31;
#pragma unroll
      for (int mt = 0; mt < 4; ++mt) {
#pragma unroll
        for (int r = 0; r < 16; ++r) {
          const long row = tm + wm + mt * 32 + (r & 3) + 8 * (r >> 2) + 4 * hi;
          Cf[cb + row * ND + col] = acc[mt][nt][r] + g;
        }
      }
    }
  }
}

// ---------------- stats combine (8 n-segment partials -> Mx, 1/sum) --------
__global__ void stats_combine(const float* __restrict__ Mp, const float* __restrict__ Sp,
                              float* __restrict__ Mx, float* __restrict__ Rs) {
  const int col = blockIdx.x * 256 + threadIdx.x;
  const int b = blockIdx.y;
  float m = -3.4e38f, s = 0.f;
  for (int k = 0; k < 8; ++k) {
    const long o = ((long)b * 8 + k) * ND + col;
    float mk = Mp[o], sk = Sp[o];
    float nm = fmaxf(m, mk);
    s = s * __expf(m - nm) + sk * __expf(mk - nm);
    m = nm;
  }
  Mx[(long)b * ND + col] = m;
  Rs[(long)b * ND + col] = 1.0f / s;
}

// attn[b,m,e] = exp(S[b,m,e] - Mx[b,e]) * Rs[b,e]  -> fp16, same layout as S
__global__ void scale_exp_kernel(const float* __restrict__ S, const float* __restrict__ Mx,
                                 const float* __restrict__ Rs, f16* __restrict__ A) {
  const long i4 = (long)blockIdx.x * 256 + threadIdx.x;  // total/4
  const long i = i4 * 4;
  const int b = (int)(i >> 22);     // N*N = 2^22
  const int col = (int)(i & 2047);  // e index (multiple of 4)
  float4 s = reinterpret_cast<const float4*>(S)[i4];
  float4 m4 = *reinterpret_cast<const float4*>(&Mx[(long)b * ND + col]);
  float4 r4 = *reinterpret_cast<const float4*>(&Rs[(long)b * ND + col]);
  f16x4 o;
  o.x = (f16)(__expf(s.x - m4.x) * r4.x);
  o.y = (f16)(__expf(s.y - m4.y) * r4.y);
  o.z = (f16)(__expf(s.z - m4.z) * r4.z);
  o.w = (f16)(__expf(s.w - m4.w) * r4.w);
  reinterpret_cast<f16x4*>(A)[i4] = o;
}

// ---------------- launch ----------------
extern "C" void kernel_launch(void* const* d_in, const int* in_sizes, int n_in,
                              void* d_out, int out_size, void* d_ws, size_t ws_size,
                              hipStream_t stream) {
  (void)in_sizes; (void)n_in; (void)out_size;
  const float* X = (const float*)d_in[0];      // [8,2048,2048]
  const float* W = (const float*)d_in[1];      // [2048,2048]
  const float* bias = (const float*)d_in[2];   // [2048]
  const float* gamma = (const float*)d_in[3];  // scalar

  char* ws = (char*)d_ws;
  f16* Xh = (f16*)(ws);                      // 67,108,864 B
  f16* Wh = (f16*)(ws + 67108864L);          //  8,388,608 B
  f16* Qh = (f16*)(ws + 75497472L);          // 67,108,864 B
  float* S = (float*)(ws + 142606336L);      // 134,217,728 B
  float* Mp = (float*)(ws + 276824064L);     //    524,288 B
  float* Sp = (float*)(ws + 277348352L);     //    524,288 B
  float* Mx = (float*)(ws + 277872640L);     //     65,536 B
  float* Rs = (float*)(ws + 277938176L);     //     65,536 B
  f16* Amat = Qh;  // overlay: Q dead after GEMM2 (stream-ordered)
  if (ws_size < 278003712UL) return;

  cvt_f16<<<32768, 256, 0, stream>>>(X, Xh, 8388608);
  cvt_f16<<<4096, 256, 0, stream>>>(W, Wh, 1048576);

  dim3 gg(8, 8, 8), bb(512);
  // Q[b,n,f] = sum_e X[b,n,e] W[f,e] + bias[f]  -> fp16
  gemm256<1><<<gg, bb, 0, stream>>>(Xh, NNL, Wh, 0L, bias, nullptr, nullptr, Qh,
                                    nullptr, nullptr);
  // S[b,n,m] = sum_e Q[b,n,e] X[b,m,e] + gamma -> fp32, + column stats
  gemm256<2><<<gg, bb, 0, stream>>>(Qh, NNL, Xh, NNL, nullptr, gamma, S, nullptr,
                                    Mp, Sp);
  stats_combine<<<dim3(8, 8), 256, 0, stream>>>(Mp, Sp, Mx, Rs);
  scale_exp_kernel<<<32768, 256, 0, stream>>>(S, Mx, Rs, Amat);
  // out[b,n,m] = sum_e X[b,n,e] attn[b,m,e]  -> fp32 d_out
  gemm256<0><<<gg, bb, 0, stream>>>(Xh, NNL, Amat, NNL, nullptr, nullptr,
                                    (float*)d_out, nullptr, nullptr, nullptr);
}

// Round 5
// 672.839 us; speedup vs baseline: 1.0485x; 1.0485x over previous
//
#include <hip/hip_runtime.h>
#include <stdint.h>

// B=8, N=E=2048.  All-fp16 single-product pipeline:
//  1) Xh = fp16(X), Wh = fp16(W)
//  2) Q = Xh·Wh^T + b   -> fp16 Qh
//  3) S = Qh·Xh^T + gamma -> fp32  (+ fused column-softmax partial stats)
//  4) stats combine (8 partials -> Mx, Rs)
//  5) attn[b,m,e] = exp(S-M)*R -> fp16 (overlays Qh)
//  6) out = Xh·attn^T -> fp32
//
// R5 = proven parts only, after R4's REGION-merge raced (intermittent
// post-timing divergence; reverted per race-screen discipline):
//  - main loop: R2's exact 4-phase PHASE skeleton (16x16x32 f16, bf-reuse,
//    2 SYNC/tile, vmcnt(8) ledger) -- post-timing-verified in R1/R2.
//  - epilogue: fused column-stats (MODE 2, 16x16 layout) -- structure
//    post-timing-verified in R3; deletes the 128-MB stats_partial dispatch.
//
// Sync skeleton (R2, passed): 4 phases/tile, 2 SYNC/tile:
//   (d,*,k0): staged t-2 P2/P3, read t P0/P1, overwritten t P2/P3
//   (e,*,k1): staged t   P0/P1, read t+1 P2/P3
//   end-P1: vmcnt(8) drains t.k1 (issued t-1 P0/P1) before P2 reads it.
//   end-P3: vmcnt(8) drains t+1.k0 (issued t-1 P2/P3) before t+1 P0 reads.
//   Tail: t=NT-2 P3 -> vmcnt(4); t=NT-1 P1 -> vmcnt(0).
// lgkmcnt(0) in SYNC retires this wave's ds_reads before the barrier, so
// post-barrier DMA overwrites are safe.  Steady state keeps 8 loads in
// flight; never drains to 0 in the main loop.
//
// LDS swizzle (0 conflicts measured): 64-B rows; stored 16-B seg
// s_lds = s_g ^ ((row>>1)&3) -- applied on the GLOBAL fetch address because
// global_load_lds forces LDS dest = base + lane*16 -- read with the inverse.
//
// Numerics bit-identical to R2 GEMM arithmetic: absmax 0.109375.

typedef _Float16 f16;
typedef f16 f16x8 __attribute__((ext_vector_type(8)));
typedef f16 f16x4 __attribute__((ext_vector_type(4)));
typedef float f32x4 __attribute__((ext_vector_type(4)));

#define ND 2048
#define NNL 4194304L  // ND*ND
#define NT 32         // K tiles of 64

static __device__ __forceinline__ void stage16(const void* g, void* l) {
  __builtin_amdgcn_global_load_lds(
      (const __attribute__((address_space(1))) uint32_t*)g,
      (__attribute__((address_space(3))) uint32_t*)l, 16, 0, 0);
}

// ---------------- fp32 -> fp16 convert ----------------
__global__ void cvt_f16(const float* __restrict__ x, f16* __restrict__ h, int n4) {
  int i = blockIdx.x * 256 + threadIdx.x;
  if (i >= n4) return;
  float4 v = reinterpret_cast<const float4*>(x)[i];
  f16x4 o;
  o.x = (f16)v.x; o.y = (f16)v.y; o.z = (f16)v.z; o.w = (f16)v.w;
  reinterpret_cast<f16x4*>(h)[i] = o;
}

// region byte base within smem: d=dbuf(0/1), o=op(0=A,1=B), kh=K-half(0/1)
#define RB(d_, o_, kh_) ((((d_) << 2) | ((o_) << 1) | (kh_)) * 16384)

// stage one 16 KiB half-region (256 rows x 32 f16): 2 x 8 KiB load-rounds.
#define STG(gp_, ro_, t_, kh_)                                           \
  do {                                                                   \
    stage16((gp_) + (long)(t_) * 128 + (kh_) * 64, smem + (ro_) + ld0);  \
    stage16((gp_) + 524288L + (long)(t_) * 128 + (kh_) * 64,             \
            smem + (ro_) + ld1);                                         \
  } while (0)

#define FENCE asm volatile("" ::: "memory")

#define SYNC(vm_)                                                        \
  do {                                                                   \
    asm volatile("s_waitcnt vmcnt(" #vm_ ") lgkmcnt(0)" ::: "memory");   \
    __builtin_amdgcn_s_barrier();                                        \
    FENCE;                                                               \
  } while (0)

// One phase (no barriers inside): mh_ = M-half, kh_ = K-half.
// RDB_=1 also (re)loads the 4 B frags (reused by the following mh_=1 phase).
#define PHASE(d_, mh_, kh_, RDB_, STAGE_)                                     \
  do {                                                                        \
    const char* ra_ = smem + RB(d_, 0, kh_) + (mh_) * 4096 + aoff;            \
    f16x8 af[4];                                                              \
    af[0] = *(const f16x8*)(ra_);                                             \
    af[1] = *(const f16x8*)(ra_ + 1024);                                      \
    af[2] = *(const f16x8*)(ra_ + 2048);                                      \
    af[3] = *(const f16x8*)(ra_ + 3072);                                      \
    if (RDB_) {                                                               \
      const char* rb_ = smem + RB(d_, 1, kh_) + boff;                         \
      bf[0] = *(const f16x8*)(rb_);                                           \
      bf[1] = *(const f16x8*)(rb_ + 1024);                                    \
      bf[2] = *(const f16x8*)(rb_ + 2048);                                    \
      bf[3] = *(const f16x8*)(rb_ + 3072);                                    \
    }                                                                         \
    STAGE_                                                                    \
    __builtin_amdgcn_s_setprio(1);                                            \
    _Pragma("unroll") for (int mt_ = 0; mt_ < 4; ++mt_) {                     \
      _Pragma("unroll") for (int nt_ = 0; nt_ < 4; ++nt_) {                   \
        acc[(mh_) * 4 + mt_][nt_] = __builtin_amdgcn_mfma_f32_16x16x32_f16(   \
            af[mt_], bf[nt_], acc[(mh_) * 4 + mt_][nt_], 0, 0, 0);            \
      }                                                                       \
    }                                                                         \
    __builtin_amdgcn_s_setprio(0);                                            \
  } while (0)

// ---------------- GEMM: C[i,j] = dot(A[i,:], B[j,:])  (row-major, K=2048)
// MODE 1: + bias[j], fp16 store
// MODE 0: + optional gamma, fp32 store
// MODE 2: + gamma, fp32 store, fused column-softmax partials -> Mp/Sp
template <int MODE>
__launch_bounds__(512, 2) __global__
void gemm256(const f16* __restrict__ A, long sA, const f16* __restrict__ B, long sB,
             const float* __restrict__ bias, const float* __restrict__ gamma,
             float* __restrict__ Cf, f16* __restrict__ Ch,
             float* __restrict__ Mp, float* __restrict__ Sp) {
  __shared__ char smem[131072];

  const int bz = blockIdx.z;
  const long tm = (long)blockIdx.y * 256;
  const long tn = (long)blockIdx.x * 256;
  const int tid = threadIdx.x;
  const int lane = tid & 63;
  const int wid = tid >> 6;
  const int wm = (wid >> 2) << 7;  // 0 / 128
  const int wn = (wid & 3) << 6;   // 0 / 64 / 128 / 192

  // staging: linear idx16 = l*512 + tid -> row = idx>>2, s_lds = idx&3,
  // fetch global seg s_g = s_lds ^ ((row>>1)&3) = (tid&3)^((tid>>3)&3)
  const int sg = (tid & 3) ^ ((tid >> 3) & 3);
  const char* gA = (const char*)(A + bz * sA + tm * ND) + (long)(tid >> 2) * 4096 + sg * 16;
  const char* gB = (const char*)(B + bz * sB + tn * ND) + (long)(tid >> 2) * 4096 + sg * 16;
  const uint32_t ld0 = tid * 16u;
  const uint32_t ld1 = 8192u + tid * 16u;

  // 16x16x32 frag reader (R2, 0 conflicts): row = base + (lane&15),
  // global seg q = lane>>4, LDS seg = q ^ ((row>>1)&3).
  const int segsw = (((lane >> 4) ^ ((lane >> 1) & 3)) << 4);  // bytes
  const int lrow = lane & 15;
  const int aoff = (wm + lrow) * 64 + segsw;
  const int boff = (wn + lrow) * 64 + segsw;

  f32x4 acc[8][4] = {};
  f16x8 bf[4];

  // prologue: t0.k0, t0.k1, t1.k0 (12 loads); vmcnt(8) drains t0.k0 only,
  // leaving {t0.k1, t1.k0} = 8 in flight = steady state.
  STG(gA, RB(0, 0, 0), 0, 0);
  STG(gB, RB(0, 1, 0), 0, 0);
  STG(gA, RB(0, 0, 1), 0, 1);
  STG(gB, RB(0, 1, 1), 0, 1);
  STG(gA, RB(1, 0, 0), 1, 0);
  STG(gB, RB(1, 1, 0), 1, 0);
  asm volatile("s_waitcnt vmcnt(8)" ::: "memory");
  __builtin_amdgcn_s_barrier();
  FENCE;

#pragma unroll 2
  for (int t = 0; t < NT - 2; ++t) {
    const int d = t & 1;
    const int e = d ^ 1;
    PHASE(d, 0, 0, 1, STG(gA, RB(e, 0, 1), t + 1, 1););
    PHASE(d, 1, 0, 0, STG(gB, RB(e, 1, 1), t + 1, 1););
    SYNC(8);
    PHASE(d, 0, 1, 1, STG(gA, RB(d, 0, 0), t + 2, 0););
    PHASE(d, 1, 1, 0, STG(gB, RB(d, 1, 0), t + 2, 0););
    SYNC(8);
  }
  {  // t = NT-2 (even => d=0, e=1)
    PHASE(0, 0, 0, 1, STG(gA, RB(1, 0, 1), NT - 1, 1););
    PHASE(0, 1, 0, 0, STG(gB, RB(1, 1, 1), NT - 1, 1););
    SYNC(8);
    PHASE(0, 0, 1, 1, ;);
    PHASE(0, 1, 1, 0, ;);
    SYNC(4);  // drains (NT-1).k0; leaves (NT-1).k1 in flight
  }
  {  // t = NT-1 (odd => d=1)
    PHASE(1, 0, 0, 1, ;);
    PHASE(1, 1, 0, 0, ;);
    SYNC(0);  // drains (NT-1).k1 before its kh=1 reads
    PHASE(1, 0, 1, 1, ;);
    PHASE(1, 1, 1, 0, ;);
    // no sync: epilogue syncs itself where needed
  }

  // epilogue: C/D layout col=lane&15, row=(lane>>4)*4+reg  [verified m89/m91]
  const int rr = (lane >> 4) << 2;
  const int cc = lane & 15;
  const long cb = (long)bz * NNL;
  if constexpr (MODE == 1) {
#pragma unroll
    for (int nt = 0; nt < 4; ++nt) {
      const long col = tn + wn + nt * 16 + cc;
      const float bj = bias[col];
#pragma unroll
      for (int mt = 0; mt < 8; ++mt) {
#pragma unroll
        for (int r = 0; r < 4; ++r) {
          const long row = tm + wm + mt * 16 + rr + r;
          Ch[cb + row * ND + col] = (f16)(acc[mt][nt][r] + bj);
        }
      }
    }
  } else if constexpr (MODE == 0) {
    const float g = gamma ? gamma[0] : 0.0f;
#pragma unroll
    for (int mt = 0; mt < 8; ++mt) {
#pragma unroll
      for (int nt = 0; nt < 4; ++nt) {
#pragma unroll
        for (int r = 0; r < 4; ++r) {
          const long row = tm + wm + mt * 16 + rr + r;
          const long col = tn + wn + nt * 16 + cc;
          Cf[cb + row * ND + col] = acc[mt][nt][r] + g;
        }
      }
    }
  } else {  // MODE 2: fp32 store + gamma + fused column-softmax partials
    const float g = gamma[0];
    __syncthreads();  // all waves done with smem tiles -> safe to reuse
    float* redm = (float*)smem;  // [8 wid][4 nt][16 cc] = 512 floats
    float* reds = redm + 512;
#pragma unroll
    for (int nt = 0; nt < 4; ++nt) {
      // lane covers col cc (of nt), rows rr..rr+3 of each of 8 mt blocks
      float ml = -3.4e38f;
#pragma unroll
      for (int mt = 0; mt < 8; ++mt)
#pragma unroll
        for (int r = 0; r < 4; ++r)
          ml = fmaxf(ml, acc[mt][nt][r] + g);
      float sl = 0.f;
#pragma unroll
      for (int mt = 0; mt < 8; ++mt)
#pragma unroll
        for (int r = 0; r < 4; ++r)
          sl += __expf(acc[mt][nt][r] + g - ml);
      // butterfly over lane bits 4,5: combine the 4 rr-stripes of column cc
#pragma unroll
      for (int off = 16; off < 64; off <<= 1) {
        float pm = __shfl_xor(ml, off, 64);
        float ps = __shfl_xor(sl, off, 64);
        float nm = fmaxf(ml, pm);
        sl = sl * __expf(ml - nm) + ps * __expf(pm - nm);
        ml = nm;
      }
      if ((lane >> 4) == 0) {
        redm[wid * 64 + nt * 16 + lrow] = ml;
        reds[wid * 64 + nt * 16 + lrow] = sl;
      }
    }
    __syncthreads();
    if (tid < 256) {
      // col = tn + tid;  pair = wm=0 wave (redm[tid]) x wm=128 (redm[256+tid])
      const float mA = redm[tid], sA = reds[tid];
      const float mB = redm[256 + tid], sB = reds[256 + tid];
      const float m = fmaxf(mA, mB);
      const float s = sA * __expf(mA - m) + sB * __expf(mB - m);
      const long o = ((long)bz * 8 + blockIdx.y) * ND + tn + tid;
      Mp[o] = m;
      Sp[o] = s;
    }
    // S store
#pragma unroll
    for (int mt = 0; mt < 8; ++mt) {
#pragma unroll
      for (int nt = 0; nt < 4; ++nt) {
#pragma unroll
        for (int r = 0; r < 4; ++r) {
          const long row = tm + wm + mt * 16 + rr + r;
          const long col = tn + wn + nt * 16 + cc;
          Cf[cb + row * ND + col] = acc[mt][nt][r] + g;
        }
      }
    }
  }
}

// ---------------- stats combine (8 n-segment partials -> Mx, 1/sum) --------
__global__ void stats_combine(const float* __restrict__ Mp, const float* __restrict__ Sp,
                              float* __restrict__ Mx, float* __restrict__ Rs) {
  const int col = blockIdx.x * 256 + threadIdx.x;
  const int b = blockIdx.y;
  float m = -3.4e38f, s = 0.f;
  for (int k = 0; k < 8; ++k) {
    const long o = ((long)b * 8 + k) * ND + col;
    float mk = Mp[o], sk = Sp[o];
    float nm = fmaxf(m, mk);
    s = s * __expf(m - nm) + sk * __expf(mk - nm);
    m = nm;
  }
  Mx[(long)b * ND + col] = m;
  Rs[(long)b * ND + col] = 1.0f / s;
}

// attn[b,m,e] = exp(S[b,m,e] - Mx[b,e]) * Rs[b,e]  -> fp16, same layout as S
__global__ void scale_exp_kernel(const float* __restrict__ S, const float* __restrict__ Mx,
                                 const float* __restrict__ Rs, f16* __restrict__ A) {
  const long i4 = (long)blockIdx.x * 256 + threadIdx.x;  // total/4
  const long i = i4 * 4;
  const int b = (int)(i >> 22);     // N*N = 2^22
  const int col = (int)(i & 2047);  // e index (multiple of 4)
  float4 s = reinterpret_cast<const float4*>(S)[i4];
  float4 m4 = *reinterpret_cast<const float4*>(&Mx[(long)b * ND + col]);
  float4 r4 = *reinterpret_cast<const float4*>(&Rs[(long)b * ND + col]);
  f16x4 o;
  o.x = (f16)(__expf(s.x - m4.x) * r4.x);
  o.y = (f16)(__expf(s.y - m4.y) * r4.y);
  o.z = (f16)(__expf(s.z - m4.z) * r4.z);
  o.w = (f16)(__expf(s.w - m4.w) * r4.w);
  reinterpret_cast<f16x4*>(A)[i4] = o;
}

// ---------------- launch ----------------
extern "C" void kernel_launch(void* const* d_in, const int* in_sizes, int n_in,
                              void* d_out, int out_size, void* d_ws, size_t ws_size,
                              hipStream_t stream) {
  (void)in_sizes; (void)n_in; (void)out_size;
  const float* X = (const float*)d_in[0];      // [8,2048,2048]
  const float* W = (const float*)d_in[1];      // [2048,2048]
  const float* bias = (const float*)d_in[2];   // [2048]
  const float* gamma = (const float*)d_in[3];  // scalar

  char* ws = (char*)d_ws;
  f16* Xh = (f16*)(ws);                      // 67,108,864 B
  f16* Wh = (f16*)(ws + 67108864L);          //  8,388,608 B
  f16* Qh = (f16*)(ws + 75497472L);          // 67,108,864 B
  float* S = (float*)(ws + 142606336L);      // 134,217,728 B
  float* Mp = (float*)(ws + 276824064L);     //    524,288 B
  float* Sp = (float*)(ws + 277348352L);     //    524,288 B
  float* Mx = (float*)(ws + 277872640L);     //     65,536 B
  float* Rs = (float*)(ws + 277938176L);     //     65,536 B
  f16* Amat = Qh;  // overlay: Q dead after GEMM2 (stream-ordered)
  if (ws_size < 278003712UL) return;

  cvt_f16<<<32768, 256, 0, stream>>>(X, Xh, 8388608);
  cvt_f16<<<4096, 256, 0, stream>>>(W, Wh, 1048576);

  dim3 gg(8, 8, 8), bb(512);
  // Q[b,n,f] = sum_e X[b,n,e] W[f,e] + bias[f]  -> fp16
  gemm256<1><<<gg, bb, 0, stream>>>(Xh, NNL, Wh, 0L, bias, nullptr, nullptr, Qh,
                                    nullptr, nullptr);
  // S[b,n,m] = sum_e Q[b,n,e] X[b,m,e] + gamma -> fp32, + column stats
  gemm256<2><<<gg, bb, 0, stream>>>(Qh, NNL, Xh, NNL, nullptr, gamma, S, nullptr,
                                    Mp, Sp);
  stats_combine<<<dim3(8, 8), 256, 0, stream>>>(Mp, Sp, Mx, Rs);
  scale_exp_kernel<<<32768, 256, 0, stream>>>(S, Mx, Rs, Amat);
  // out[b,n,m] = sum_e X[b,n,e] attn[b,m,e]  -> fp32 d_out
  gemm256<0><<<gg, bb, 0, stream>>>(Xh, NNL, Amat, NNL, nullptr, nullptr,
                                    (float*)d_out, nullptr, nullptr, nullptr);
}

// Round 6
// 627.617 us; speedup vs baseline: 1.1240x; 1.0721x over previous
//
#include <hip/hip_runtime.h>
#include <stdint.h>

// B=8, N=E=2048.  All-fp16 single-product pipeline:
//  1) Xh = fp16(X), Wh = fp16(W)
//  2) Q = Xh·Wh^T + b   -> fp16 Qh
//  3) S = Qh·Xh^T + gamma -> fp16 Sh (+ fused column-softmax partial stats,
//     computed FROM the f16-rounded scores so softmax(s16) is exact and the
//     dominant-entry rounding cancels for peaked columns)
//  4) stats combine (8 partials -> Mx, Rs)
//  5) attn[b,m,e] = exp(Sh-M)*R -> fp16 (overlays Qh)
//  6) out = Xh·attn^T -> fp32
//
// R6 vs R5 (672.8 us; GEMMs invariant at ~153-155 us / MfmaUtil ~40% across
// ALL schedule variants R1-R4):
//  (a) XCD-aware 2D block swizzle.  DMA staging = 1.07 GB/dispatch ~ 6.9 TB/s
//      aggregate; default linear%8 XCD round-robin puts the 8 blocks sharing
//      an A-panel on 8 DIFFERENT XCDs -> ~0.5 GB/dispatch of A re-staging is
//      served by L3 (~3.4 TB/s sustained) -- the schedule-invariant suspect.
//      Remap: xcd = blockIdx.x (= linear%8 since linear is x-fastest),
//      sub = blockIdx.y; bx = (xcd&1)*4 + (sub&3), by = (xcd>>1)*2 + (sub>>2)
//      -> each XCD owns a 4(tn) x 2(tm) sub-grid: A-panels hit L3 2x (was 8x),
//      B-panels 4x (was 8x); rest from own-XCD L2.  Bijective per z.  Pure
//      index remap: no sync or numeric change.
//  (b) S stored as f16 (GEMM2 MODE2 stores f16 via Ch; scale_exp reads f16):
//      saves ~134 MB HBM.  Stats from rounded scores keep attn = exact
//      softmax(s16): error second-order even for one-hot columns.
//
// Main loop = R2/R5's post-timing-verified skeleton, UNTOUCHED:
// 4 phases/tile, 2 SYNC/tile, vmcnt(8) steady ledger (see R5 comments),
// lgkmcnt(0) folded into SYNC, 8 loads always in flight.
//
// LDS swizzle (0 conflicts measured): 64-B rows; stored 16-B seg
// s_lds = s_g ^ ((row>>1)&3) on the GLOBAL fetch address (global_load_lds
// forces LDS dest = base + lane*16), read with the inverse.

typedef _Float16 f16;
typedef f16 f16x8 __attribute__((ext_vector_type(8)));
typedef f16 f16x4 __attribute__((ext_vector_type(4)));
typedef float f32x4 __attribute__((ext_vector_type(4)));

#define ND 2048
#define NNL 4194304L  // ND*ND
#define NT 32         // K tiles of 64

static __device__ __forceinline__ void stage16(const void* g, void* l) {
  __builtin_amdgcn_global_load_lds(
      (const __attribute__((address_space(1))) uint32_t*)g,
      (__attribute__((address_space(3))) uint32_t*)l, 16, 0, 0);
}

// ---------------- fp32 -> fp16 convert ----------------
__global__ void cvt_f16(const float* __restrict__ x, f16* __restrict__ h, int n4) {
  int i = blockIdx.x * 256 + threadIdx.x;
  if (i >= n4) return;
  float4 v = reinterpret_cast<const float4*>(x)[i];
  f16x4 o;
  o.x = (f16)v.x; o.y = (f16)v.y; o.z = (f16)v.z; o.w = (f16)v.w;
  reinterpret_cast<f16x4*>(h)[i] = o;
}

// region byte base within smem: d=dbuf(0/1), o=op(0=A,1=B), kh=K-half(0/1)
#define RB(d_, o_, kh_) ((((d_) << 2) | ((o_) << 1) | (kh_)) * 16384)

// stage one 16 KiB half-region (256 rows x 32 f16): 2 x 8 KiB load-rounds.
#define STG(gp_, ro_, t_, kh_)                                           \
  do {                                                                   \
    stage16((gp_) + (long)(t_) * 128 + (kh_) * 64, smem + (ro_) + ld0);  \
    stage16((gp_) + 524288L + (long)(t_) * 128 + (kh_) * 64,             \
            smem + (ro_) + ld1);                                         \
  } while (0)

#define FENCE asm volatile("" ::: "memory")

#define SYNC(vm_)                                                        \
  do {                                                                   \
    asm volatile("s_waitcnt vmcnt(" #vm_ ") lgkmcnt(0)" ::: "memory");   \
    __builtin_amdgcn_s_barrier();                                        \
    FENCE;                                                               \
  } while (0)

// One phase (no barriers inside): mh_ = M-half, kh_ = K-half.
// RDB_=1 also (re)loads the 4 B frags (reused by the following mh_=1 phase).
#define PHASE(d_, mh_, kh_, RDB_, STAGE_)                                     \
  do {                                                                        \
    const char* ra_ = smem + RB(d_, 0, kh_) + (mh_) * 4096 + aoff;            \
    f16x8 af[4];                                                              \
    af[0] = *(const f16x8*)(ra_);                                             \
    af[1] = *(const f16x8*)(ra_ + 1024);                                      \
    af[2] = *(const f16x8*)(ra_ + 2048);                                      \
    af[3] = *(const f16x8*)(ra_ + 3072);                                      \
    if (RDB_) {                                                               \
      const char* rb_ = smem + RB(d_, 1, kh_) + boff;                         \
      bf[0] = *(const f16x8*)(rb_);                                           \
      bf[1] = *(const f16x8*)(rb_ + 1024);                                    \
      bf[2] = *(const f16x8*)(rb_ + 2048);                                    \
      bf[3] = *(const f16x8*)(rb_ + 3072);                                    \
    }                                                                         \
    STAGE_                                                                    \
    __builtin_amdgcn_s_setprio(1);                                            \
    _Pragma("unroll") for (int mt_ = 0; mt_ < 4; ++mt_) {                     \
      _Pragma("unroll") for (int nt_ = 0; nt_ < 4; ++nt_) {                   \
        acc[(mh_) * 4 + mt_][nt_] = __builtin_amdgcn_mfma_f32_16x16x32_f16(   \
            af[mt_], bf[nt_], acc[(mh_) * 4 + mt_][nt_], 0, 0, 0);            \
      }                                                                       \
    }                                                                         \
    __builtin_amdgcn_s_setprio(0);                                            \
  } while (0)

// ---------------- GEMM: C[i,j] = dot(A[i,:], B[j,:])  (row-major, K=2048)
// MODE 1: + bias[j], fp16 store (Ch)
// MODE 0: fp32 store (Cf)
// MODE 2: + gamma, f16 store (Ch) + fused column-softmax partials -> Mp/Sp
template <int MODE>
__launch_bounds__(512, 2) __global__
void gemm256(const f16* __restrict__ A, long sA, const f16* __restrict__ B, long sB,
             const float* __restrict__ bias, const float* __restrict__ gamma,
             float* __restrict__ Cf, f16* __restrict__ Ch,
             float* __restrict__ Mp, float* __restrict__ Sp) {
  __shared__ char smem[131072];

  const int bz = blockIdx.z;
  // XCD-aware remap: xcd = blockIdx.x (= dispatch-linear % 8, x-fastest),
  // sub = blockIdx.y.  XCD k owns tn in {(k&1)*4 .. +3}, tm in {(k>>1)*2, +1}.
  const int bx = ((blockIdx.x & 1) << 2) | (blockIdx.y & 3);   // tn index
  const int by = (((blockIdx.x >> 1) & 3) << 1) | (blockIdx.y >> 2);  // tm idx
  const long tm = (long)by * 256;
  const long tn = (long)bx * 256;
  const int tid = threadIdx.x;
  const int lane = tid & 63;
  const int wid = tid >> 6;
  const int wm = (wid >> 2) << 7;  // 0 / 128
  const int wn = (wid & 3) << 6;   // 0 / 64 / 128 / 192

  // staging: linear idx16 = l*512 + tid -> row = idx>>2, s_lds = idx&3,
  // fetch global seg s_g = s_lds ^ ((row>>1)&3) = (tid&3)^((tid>>3)&3)
  const int sg = (tid & 3) ^ ((tid >> 3) & 3);
  const char* gA = (const char*)(A + bz * sA + tm * ND) + (long)(tid >> 2) * 4096 + sg * 16;
  const char* gB = (const char*)(B + bz * sB + tn * ND) + (long)(tid >> 2) * 4096 + sg * 16;
  const uint32_t ld0 = tid * 16u;
  const uint32_t ld1 = 8192u + tid * 16u;

  // 16x16x32 frag reader (0 conflicts): row = base + (lane&15),
  // global seg q = lane>>4, LDS seg = q ^ ((row>>1)&3).
  const int segsw = (((lane >> 4) ^ ((lane >> 1) & 3)) << 4);  // bytes
  const int lrow = lane & 15;
  const int aoff = (wm + lrow) * 64 + segsw;
  const int boff = (wn + lrow) * 64 + segsw;

  f32x4 acc[8][4] = {};
  f16x8 bf[4];

  // prologue: t0.k0, t0.k1, t1.k0 (12 loads); vmcnt(8) drains t0.k0 only,
  // leaving {t0.k1, t1.k0} = 8 in flight = steady state.
  STG(gA, RB(0, 0, 0), 0, 0);
  STG(gB, RB(0, 1, 0), 0, 0);
  STG(gA, RB(0, 0, 1), 0, 1);
  STG(gB, RB(0, 1, 1), 0, 1);
  STG(gA, RB(1, 0, 0), 1, 0);
  STG(gB, RB(1, 1, 0), 1, 0);
  asm volatile("s_waitcnt vmcnt(8)" ::: "memory");
  __builtin_amdgcn_s_barrier();
  FENCE;

#pragma unroll 2
  for (int t = 0; t < NT - 2; ++t) {
    const int d = t & 1;
    const int e = d ^ 1;
    PHASE(d, 0, 0, 1, STG(gA, RB(e, 0, 1), t + 1, 1););
    PHASE(d, 1, 0, 0, STG(gB, RB(e, 1, 1), t + 1, 1););
    SYNC(8);
    PHASE(d, 0, 1, 1, STG(gA, RB(d, 0, 0), t + 2, 0););
    PHASE(d, 1, 1, 0, STG(gB, RB(d, 1, 0), t + 2, 0););
    SYNC(8);
  }
  {  // t = NT-2 (even => d=0, e=1)
    PHASE(0, 0, 0, 1, STG(gA, RB(1, 0, 1), NT - 1, 1););
    PHASE(0, 1, 0, 0, STG(gB, RB(1, 1, 1), NT - 1, 1););
    SYNC(8);
    PHASE(0, 0, 1, 1, ;);
    PHASE(0, 1, 1, 0, ;);
    SYNC(4);  // drains (NT-1).k0; leaves (NT-1).k1 in flight
  }
  {  // t = NT-1 (odd => d=1)
    PHASE(1, 0, 0, 1, ;);
    PHASE(1, 1, 0, 0, ;);
    SYNC(0);  // drains (NT-1).k1 before its kh=1 reads
    PHASE(1, 0, 1, 1, ;);
    PHASE(1, 1, 1, 0, ;);
    // no sync: epilogue syncs itself where needed
  }

  // epilogue: C/D layout col=lane&15, row=(lane>>4)*4+reg  [verified m89/m91]
  const int rr = (lane >> 4) << 2;
  const int cc = lane & 15;
  const long cb = (long)bz * NNL;
  if constexpr (MODE == 1) {
#pragma unroll
    for (int nt = 0; nt < 4; ++nt) {
      const long col = tn + wn + nt * 16 + cc;
      const float bj = bias[col];
#pragma unroll
      for (int mt = 0; mt < 8; ++mt) {
#pragma unroll
        for (int r = 0; r < 4; ++r) {
          const long row = tm + wm + mt * 16 + rr + r;
          Ch[cb + row * ND + col] = (f16)(acc[mt][nt][r] + bj);
        }
      }
    }
  } else if constexpr (MODE == 0) {
#pragma unroll
    for (int mt = 0; mt < 8; ++mt) {
#pragma unroll
      for (int nt = 0; nt < 4; ++nt) {
#pragma unroll
        for (int r = 0; r < 4; ++r) {
          const long row = tm + wm + mt * 16 + rr + r;
          const long col = tn + wn + nt * 16 + cc;
          Cf[cb + row * ND + col] = acc[mt][nt][r];
        }
      }
    }
  } else {  // MODE 2: f16 score store + fused column-softmax partials
    const float g = gamma[0];
    // round scores to f16 FIRST; all stats from the rounded values so that
    // attn = exact softmax(s16) (dominant-entry rounding cancels).
#pragma unroll
    for (int mt = 0; mt < 8; ++mt)
#pragma unroll
      for (int nt = 0; nt < 4; ++nt)
#pragma unroll
        for (int r = 0; r < 4; ++r)
          acc[mt][nt][r] = (float)(f16)(acc[mt][nt][r] + g);
    __syncthreads();  // all waves done with smem tiles -> safe to reuse
    float* redm = (float*)smem;  // [8 wid][4 nt][16 cc] = 512 floats
    float* reds = redm + 512;
#pragma unroll
    for (int nt = 0; nt < 4; ++nt) {
      // lane covers col cc (of nt), rows rr..rr+3 of each of 8 mt blocks
      float ml = -3.4e38f;
#pragma unroll
      for (int mt = 0; mt < 8; ++mt)
#pragma unroll
        for (int r = 0; r < 4; ++r)
          ml = fmaxf(ml, acc[mt][nt][r]);
      float sl = 0.f;
#pragma unroll
      for (int mt = 0; mt < 8; ++mt)
#pragma unroll
        for (int r = 0; r < 4; ++r)
          sl += __expf(acc[mt][nt][r] - ml);
      // butterfly over lane bits 4,5: combine the 4 rr-stripes of column cc
#pragma unroll
      for (int off = 16; off < 64; off <<= 1) {
        float pm = __shfl_xor(ml, off, 64);
        float ps = __shfl_xor(sl, off, 64);
        float nm = fmaxf(ml, pm);
        sl = sl * __expf(ml - nm) + ps * __expf(pm - nm);
        ml = nm;
      }
      if ((lane >> 4) == 0) {
        redm[wid * 64 + nt * 16 + lrow] = ml;
        reds[wid * 64 + nt * 16 + lrow] = sl;
      }
    }
    __syncthreads();
    if (tid < 256) {
      // col = tn + tid;  pair = wm=0 wave (redm[tid]) x wm=128 (redm[256+tid])
      const float mA = redm[tid], sA = reds[tid];
      const float mB = redm[256 + tid], sB = reds[256 + tid];
      const float m = fmaxf(mA, mB);
      const float s = sA * __expf(mA - m) + sB * __expf(mB - m);
      const long o = ((long)bz * 8 + by) * ND + tn + tid;
      Mp[o] = m;
      Sp[o] = s;
    }
    // S store (f16; acc already rounded so this conversion is exact)
#pragma unroll
    for (int mt = 0; mt < 8; ++mt) {
#pragma unroll
      for (int nt = 0; nt < 4; ++nt) {
#pragma unroll
        for (int r = 0; r < 4; ++r) {
          const long row = tm + wm + mt * 16 + rr + r;
          const long col = tn + wn + nt * 16 + cc;
          Ch[cb + row * ND + col] = (f16)acc[mt][nt][r];
        }
      }
    }
  }
}

// ---------------- stats combine (8 n-segment partials -> Mx, 1/sum) --------
__global__ void stats_combine(const float* __restrict__ Mp, const float* __restrict__ Sp,
                              float* __restrict__ Mx, float* __restrict__ Rs) {
  const int col = blockIdx.x * 256 + threadIdx.x;
  const int b = blockIdx.y;
  float m = -3.4e38f, s = 0.f;
  for (int k = 0; k < 8; ++k) {
    const long o = ((long)b * 8 + k) * ND + col;
    float mk = Mp[o], sk = Sp[o];
    float nm = fmaxf(m, mk);
    s = s * __expf(m - nm) + sk * __expf(mk - nm);
    m = nm;
  }
  Mx[(long)b * ND + col] = m;
  Rs[(long)b * ND + col] = 1.0f / s;
}

// attn[b,m,e] = exp(Sh[b,m,e] - Mx[b,e]) * Rs[b,e]  -> fp16, same layout as Sh
__global__ void scale_exp_kernel(const f16* __restrict__ S, const float* __restrict__ Mx,
                                 const float* __restrict__ Rs, f16* __restrict__ A) {
  const long i8 = (long)blockIdx.x * 256 + threadIdx.x;  // total/8
  const long i = i8 * 8;
  const int b = (int)(i >> 22);     // N*N = 2^22
  const int col = (int)(i & 2047);  // e index (multiple of 8)
  f16x8 s = reinterpret_cast<const f16x8*>(S)[i8];
  const float* mp = &Mx[(long)b * ND + col];
  const float* rp = &Rs[(long)b * ND + col];
  float4 m0 = *reinterpret_cast<const float4*>(mp);
  float4 m1 = *reinterpret_cast<const float4*>(mp + 4);
  float4 r0 = *reinterpret_cast<const float4*>(rp);
  float4 r1 = *reinterpret_cast<const float4*>(rp + 4);
  f16x8 o;
  o[0] = (f16)(__expf((float)s[0] - m0.x) * r0.x);
  o[1] = (f16)(__expf((float)s[1] - m0.y) * r0.y);
  o[2] = (f16)(__expf((float)s[2] - m0.z) * r0.z);
  o[3] = (f16)(__expf((float)s[3] - m0.w) * r0.w);
  o[4] = (f16)(__expf((float)s[4] - m1.x) * r1.x);
  o[5] = (f16)(__expf((float)s[5] - m1.y) * r1.y);
  o[6] = (f16)(__expf((float)s[6] - m1.z) * r1.z);
  o[7] = (f16)(__expf((float)s[7] - m1.w) * r1.w);
  reinterpret_cast<f16x8*>(A)[i8] = o;
}

// ---------------- launch ----------------
extern "C" void kernel_launch(void* const* d_in, const int* in_sizes, int n_in,
                              void* d_out, int out_size, void* d_ws, size_t ws_size,
                              hipStream_t stream) {
  (void)in_sizes; (void)n_in; (void)out_size;
  const float* X = (const float*)d_in[0];      // [8,2048,2048]
  const float* W = (const float*)d_in[1];      // [2048,2048]
  const float* bias = (const float*)d_in[2];   // [2048]
  const float* gamma = (const float*)d_in[3];  // scalar

  char* ws = (char*)d_ws;
  f16* Xh = (f16*)(ws);                      // 67,108,864 B
  f16* Wh = (f16*)(ws + 67108864L);          //  8,388,608 B
  f16* Qh = (f16*)(ws + 75497472L);          // 67,108,864 B
  f16* Sh = (f16*)(ws + 142606336L);         // 67,108,864 B (f16 scores)
  float* Mp = (float*)(ws + 276824064L);     //    524,288 B
  float* Sp = (float*)(ws + 277348352L);     //    524,288 B
  float* Mx = (float*)(ws + 277872640L);     //     65,536 B
  float* Rs = (float*)(ws + 277938176L);     //     65,536 B
  f16* Amat = Qh;  // overlay: Q dead after GEMM2 (stream-ordered)
  if (ws_size < 278003712UL) return;

  cvt_f16<<<32768, 256, 0, stream>>>(X, Xh, 8388608);
  cvt_f16<<<4096, 256, 0, stream>>>(W, Wh, 1048576);

  dim3 gg(8, 8, 8), bb(512);
  // Q[b,n,f] = sum_e X[b,n,e] W[f,e] + bias[f]  -> fp16
  gemm256<1><<<gg, bb, 0, stream>>>(Xh, NNL, Wh, 0L, bias, nullptr, nullptr, Qh,
                                    nullptr, nullptr);
  // S[b,n,m] = sum_e Q[b,n,e] X[b,m,e] + gamma -> f16 Sh, + column stats
  gemm256<2><<<gg, bb, 0, stream>>>(Qh, NNL, Xh, NNL, nullptr, gamma, nullptr, Sh,
                                    Mp, Sp);
  stats_combine<<<dim3(8, 8), 256, 0, stream>>>(Mp, Sp, Mx, Rs);
  scale_exp_kernel<<<16384, 256, 0, stream>>>(Sh, Mx, Rs, Amat);
  // out[b,n,m] = sum_e X[b,n,e] attn[b,m,e]  -> fp32 d_out
  gemm256<0><<<gg, bb, 0, stream>>>(Xh, NNL, Amat, NNL, nullptr, nullptr,
                                    (float*)d_out, nullptr, nullptr, nullptr);
}